// Round 9
// baseline (35.985 us; speedup 1.0000x reference)
//
#include <hip/hip_runtime.h>
#include <hip/hip_bf16.h>
#include <math.h>

#define N_VOX 4096
#define LOG2E 1.44269504f

typedef __bf16 bf16x8 __attribute__((ext_vector_type(8)));
typedef __bf16 bf16x4 __attribute__((ext_vector_type(4)));
typedef float f32x4 __attribute__((ext_vector_type(4)));

// ws layout (BYTES):
//   qt bf16[2][4096][32] @ 0  (PRE-SCALED by log2e; cols 16..31 zero)
//   kt bf16[2][4096][32] @ 524288
//   vp fp8  packed       @ 1048576
//     byte index: (((b*64+jt)*8+ct)*2+cn)*512 + lane*8 + e
#define QT_OFF  0
#define KT_OFF  524288
#define VP_OFF  1048576

__device__ __forceinline__ f32x4 mfma16(f32x4 a, f32x4 b, f32x4 c) {
  return __builtin_amdgcn_mfma_f32_16x16x32_bf16(
      __builtin_bit_cast(bf16x8, a), __builtin_bit_cast(bf16x8, b), c, 0, 0, 0);
}
__device__ __forceinline__ void pin(f32x4& v) { asm volatile("" : "+v"(v)); }
__device__ __forceinline__ void pinl(long& v) { asm volatile("" : "+v"(v)); }

__device__ __forceinline__ unsigned f32_to_fp8x4(float a, float b, float c, float d) {
  int v = __builtin_amdgcn_cvt_pk_fp8_f32(a, b, 0, false);
  v = __builtin_amdgcn_cvt_pk_fp8_f32(c, d, v, true);
  return (unsigned)v;
}
__device__ __forceinline__ unsigned char f32_to_fp8(float a) {
  return (unsigned char)(__builtin_amdgcn_cvt_pk_fp8_f32(a, a, 0, false) & 0xff);
}

// ---------------------------------------------------------------------------
// Kernel 1: q/k/v projections as MFMA GEMM.
// w A-fragments loaded directly from global (L2-resident, 80 KB total) —
// no w LDS staging. grid = 2 x 128 n-tiles of 32, 256 threads.
// ---------------------------------------------------------------------------
__global__ __launch_bounds__(256) void proj_kernel(
    const float* __restrict__ x,
    const float* __restrict__ wq, const float* __restrict__ bq,
    const float* __restrict__ wk, const float* __restrict__ bk,
    const float* __restrict__ wv, const float* __restrict__ bv,
    unsigned char* __restrict__ ws8) {
  __shared__ __bf16 xs[32 * 136];    // [n][c] pad 136   8.7 KB

  const int t   = threadIdx.x;
  const int bid = blockIdx.x;        // 256 = 2 * 128
  const int b   = bid >> 7;
  const int n0  = (bid & 127) * 32;

  // stage x tile transposed
  for (int idx = t; idx < 128 * 8; idx += 256) {
    int c = idx >> 3, v4 = idx & 7;
    float4 xv = *reinterpret_cast<const float4*>(
        x + (size_t)(b * 128 + c) * N_VOX + n0 + v4 * 4);
    xs[(v4 * 4 + 0) * 136 + c] = (__bf16)xv.x;
    xs[(v4 * 4 + 1) * 136 + c] = (__bf16)xv.y;
    xs[(v4 * 4 + 2) * 136 + c] = (__bf16)xv.z;
    xs[(v4 * 4 + 3) * 136 + c] = (__bf16)xv.w;
  }
  __syncthreads();

  const int w = t >> 6, lane = t & 63;
  const int cq = lane & 15, g = lane >> 4, g8 = g * 8, g4 = g * 4;

  __bf16* qt = reinterpret_cast<__bf16*>(ws8 + QT_OFF);
  __bf16* kt = reinterpret_cast<__bf16*>(ws8 + KT_OFF);
  unsigned char* vp = ws8 + VP_OFF;
  const f32x4 zero4 = {0.f, 0.f, 0.f, 0.f};

  for (int ot = w; ot < 10; ot += 4) {
    const float* wbase = (ot == 0) ? wq : (ot == 1) ? wk : wv + (ot - 2) * 16 * 128;
    const float* bias  = (ot == 0) ? bq : (ot == 1) ? bk : bv + (ot - 2) * 16;
    const float* wrow  = wbase + cq * 128;

    f32x4 acc[2] = {zero4, zero4};
#pragma unroll
    for (int ks = 0; ks < 4; ++ks) {
      // A-fragment direct from global: w[row=cq][k=ks*32+g8 .. +7], fp32
      float4 f0 = *reinterpret_cast<const float4*>(wrow + ks * 32 + g8);
      float4 f1 = *reinterpret_cast<const float4*>(wrow + ks * 32 + g8 + 4);
      bf16x8 af;
      af[0] = (__bf16)f0.x; af[1] = (__bf16)f0.y;
      af[2] = (__bf16)f0.z; af[3] = (__bf16)f0.w;
      af[4] = (__bf16)f1.x; af[5] = (__bf16)f1.y;
      af[6] = (__bf16)f1.z; af[7] = (__bf16)f1.w;
#pragma unroll
      for (int nf = 0; nf < 2; ++nf) {
        bf16x8 bfr = *reinterpret_cast<const bf16x8*>(
            &xs[(nf * 16 + cq) * 136 + ks * 32 + g8]);
        acc[nf] = __builtin_amdgcn_mfma_f32_16x16x32_bf16(af, bfr, acc[nf], 0, 0, 0);
      }
    }

    float4 bl = *reinterpret_cast<const float4*>(bias + g4);
    const float* blp = reinterpret_cast<const float*>(&bl);
#pragma unroll
    for (int nf = 0; nf < 2; ++nf) {
      int n = n0 + nf * 16 + cq;
#pragma unroll
      for (int v = 0; v < 4; ++v) {
        float val = acc[nf][v] + blp[v];
        int o = g4 + v;
        if (ot == 0) {
          // q pre-scaled by log2e -> QK^T lands in log2 domain
          qt[(size_t)(b * 4096 + n) * 32 + o] = (__bf16)(val * LOG2E);
          qt[(size_t)(b * 4096 + n) * 32 + 16 + o] = (__bf16)0.f;
        } else if (ot == 1) {
          kt[(size_t)(b * 4096 + n) * 32 + o] = (__bf16)val;
          kt[(size_t)(b * 4096 + n) * 32 + 16 + o] = (__bf16)0.f;
        } else {
          int c  = (ot - 2) * 16 + o;
          int jt = n >> 6, j_in = n & 63;
          int cn = j_in >> 5, gg = (j_in & 31) >> 3, e = j_in & 7;
          int lt = (c & 15) | (gg << 4);
          vp[((((size_t)b * 64 + jt) * 8 + (c >> 4)) * 2 + cn) * 512 + lt * 8 + e]
              = f32_to_fp8(val);
        }
      }
    }
  }
}

// ---------------------------------------------------------------------------
// Kernel 2: fused flash attention. grid = 256 (b x 128 q-tiles of 32),
// 512 threads = 8 waves, each wave: 32 q x 512 keys (8 tiles of 64).
// log2-domain softmax: p = exp2(s - m) <= 2^8 = 256 < 448 (no clamp needed).
// Software pipeline: QK^T(t+1) runs between P-store(t) and PV(t).
// ---------------------------------------------------------------------------
__global__ __launch_bounds__(512, 2) void attn_kernel(
    const unsigned char* __restrict__ ws8,
    const float* __restrict__ x,
    const float* __restrict__ gamma_p,
    float* __restrict__ out) {
  __shared__ __align__(16) unsigned char ps[8][32 * 72];  // P^T fp8, 18.4 KB
  __shared__ float o_lds[4][128][33];                     // 67.6 KB
  __shared__ float m_lds[8][32], l_lds[8][32], lstar_lds[32];

  const int t    = threadIdx.x;
  const int w    = t >> 6;          // wave 0..7
  const int lane = t & 63;
  const int cq   = lane & 15;
  const int g    = lane >> 4;
  const int g8   = g * 8;
  const int g4   = g * 4;

  // XCD-bijective swizzle: XCDs 0-3 -> batch 0, XCDs 4-7 -> batch 1
  const int raw = blockIdx.x;            // 256
  const int xcd = raw & 7;
  const int b   = xcd >> 2;
  const int qt0 = ((raw >> 3) * 4 + (xcd & 3)) * 32;

  const __bf16* qt = reinterpret_cast<const __bf16*>(ws8 + QT_OFF);
  const __bf16* kt = reinterpret_cast<const __bf16*>(ws8 + KT_OFF);
  const unsigned char* vp = ws8 + VP_OFF;

  f32x4 qfrag[2];
#pragma unroll
  for (int qf = 0; qf < 2; ++qf)
    qfrag[qf] = *reinterpret_cast<const f32x4*>(
        qt + (size_t)(b * 4096 + qt0 + qf * 16 + cq) * 32 + g8);

  const f32x4 zero4 = {0.f, 0.f, 0.f, 0.f};
  f32x4 acc[8][2];
#pragma unroll
  for (int ct = 0; ct < 8; ++ct) { acc[ct][0] = zero4; acc[ct][1] = zero4; }
  float m0 = -1e30f, m1 = -1e30f, l0 = 0.f, l1 = 0.f;

  unsigned char* psw0 = &ps[w][cq * 72];
  unsigned char* psw1 = &ps[w][(16 + cq) * 72];
  const __bf16* kbase = kt + (size_t)(b * 4096 + cq) * 32 + g8;
  const unsigned char* vbase = vp + (size_t)b * 524288 + lane * 8;

  const int jt_base = w * 8;             // wave covers j-tiles [w*8, w*8+8)

  // ---- prologue: kf(0) -> sf(0); kfA holds kf(1) ----
  f32x4 kf0[4], kfA[4];
#pragma unroll
  for (int s = 0; s < 4; ++s)
    kf0[s] = *reinterpret_cast<const f32x4*>(
        kbase + (size_t)(jt_base * 64 + s * 16) * 32);
#pragma unroll
  for (int s = 0; s < 4; ++s)
    kfA[s] = *reinterpret_cast<const f32x4*>(
        kbase + (size_t)((jt_base + 1) * 64 + s * 16) * 32);
#pragma unroll
  for (int s = 0; s < 4; ++s) pin(kf0[s]);

  f32x4 sf[4][2];
#pragma unroll
  for (int s = 0; s < 4; ++s) {
    sf[s][0] = mfma16(kf0[s], qfrag[0], zero4);
    sf[s][1] = mfma16(kf0[s], qfrag[1], zero4);
  }

#pragma unroll 1
  for (int tile = 0; tile < 8; ++tile) {
    const int jt = jt_base + tile;

    // ---- issue V(t) loads + K(t+2) loads ----
    long vf[2][8];
#pragma unroll
    for (int cn = 0; cn < 2; ++cn)
#pragma unroll
      for (int ct = 0; ct < 8; ++ct)
        vf[cn][ct] = *reinterpret_cast<const long*>(
            vbase + ((((size_t)jt * 8 + ct) * 2 + cn) << 9));
    f32x4 kfB[4];
    const int j2 = jt_base + ((tile + 2) & 7);
#pragma unroll
    for (int s = 0; s < 4; ++s)
      kfB[s] = *reinterpret_cast<const f32x4*>(
          kbase + (size_t)(j2 * 64 + s * 16) * 32);

    // ---- online softmax on sf (tile t), log2 domain ----
    float tmax0 = sf[0][0][0], tmax1 = sf[0][1][0];
#pragma unroll
    for (int s = 0; s < 4; ++s)
#pragma unroll
      for (int v = 0; v < 4; ++v) {
        tmax0 = fmaxf(tmax0, sf[s][0][v]);
        tmax1 = fmaxf(tmax1, sf[s][1][v]);
      }
    tmax0 = fmaxf(tmax0, __shfl_xor(tmax0, 16));
    tmax0 = fmaxf(tmax0, __shfl_xor(tmax0, 32));
    tmax1 = fmaxf(tmax1, __shfl_xor(tmax1, 16));
    tmax1 = fmaxf(tmax1, __shfl_xor(tmax1, 32));

    if (__any((tmax0 > m0 + 8.0f) || (tmax1 > m1 + 8.0f))) {   // defer-max
      float m0n = fmaxf(m0, tmax0), m1n = fmaxf(m1, tmax1);
      float sc0 = exp2f(m0 - m0n), sc1 = exp2f(m1 - m1n);
#pragma unroll
      for (int ct = 0; ct < 8; ++ct) { acc[ct][0] *= sc0; acc[ct][1] *= sc1; }
      l0 *= sc0; l1 *= sc1;
      m0 = m0n; m1 = m1n;
    }

    // p = exp2(s - m) <= 2^8 = 256 < 448 (e4m3 max) — guaranteed by defer.
    float psum0 = 0.f, psum1 = 0.f;
#pragma unroll
    for (int s = 0; s < 4; ++s) {
      float p0[4], p1[4];
#pragma unroll
      for (int v = 0; v < 4; ++v) {
        p0[v] = exp2f(sf[s][0][v] - m0);
        p1[v] = exp2f(sf[s][1][v] - m1);
        psum0 += p0[v]; psum1 += p1[v];
      }
      *reinterpret_cast<unsigned*>(psw0 + s * 16 + g4) =
          f32_to_fp8x4(p0[0], p0[1], p0[2], p0[3]);
      *reinterpret_cast<unsigned*>(psw1 + s * 16 + g4) =
          f32_to_fp8x4(p1[0], p1[1], p1[2], p1[3]);
    }
    psum0 += __shfl_xor(psum0, 16); psum0 += __shfl_xor(psum0, 32);
    psum1 += __shfl_xor(psum1, 16); psum1 += __shfl_xor(psum1, 32);
    l0 += psum0; l1 += psum1;

    // ---- pipelined QK^T for tile t+1 (hides P LDS write->read latency) ----
    if (tile < 7) {
#pragma unroll
      for (int s = 0; s < 4; ++s) pin(kfA[s]);
#pragma unroll
      for (int s = 0; s < 4; ++s) {
        sf[s][0] = mfma16(kfA[s], qfrag[0], zero4);
        sf[s][1] = mfma16(kfA[s], qfrag[1], zero4);
      }
    }

    // ---- PV (fp8): pin loads (batched wait), then 32 MFMAs ----
#pragma unroll
    for (int cn = 0; cn < 2; ++cn)
#pragma unroll
      for (int ct = 0; ct < 8; ++ct) pinl(vf[cn][ct]);

    __builtin_amdgcn_s_setprio(1);
#pragma unroll
    for (int cn = 0; cn < 2; ++cn) {
      long pf0 = *reinterpret_cast<const long*>(psw0 + cn * 32 + g8);
      long pf1 = *reinterpret_cast<const long*>(psw1 + cn * 32 + g8);
#pragma unroll
      for (int ct = 0; ct < 8; ++ct) {
        acc[ct][0] = __builtin_amdgcn_mfma_f32_16x16x32_fp8_fp8(
            vf[cn][ct], pf0, acc[ct][0], 0, 0, 0);
        acc[ct][1] = __builtin_amdgcn_mfma_f32_16x16x32_fp8_fp8(
            vf[cn][ct], pf1, acc[ct][1], 0, 0, 0);
      }
    }
    __builtin_amdgcn_s_setprio(0);

    // rotate K prefetch registers
#pragma unroll
    for (int s = 0; s < 4; ++s) kfA[s] = kfB[s];
  }

  // ---- cross-wave merge (8 partials, log2 domain) ----
  if (lane < 16) {
    m_lds[w][cq] = m0; m_lds[w][16 + cq] = m1;
    l_lds[w][cq] = l0; l_lds[w][16 + cq] = l1;
  }
  __syncthreads();

  float mstar0 = m_lds[0][cq],      mstar1 = m_lds[0][16 + cq];
#pragma unroll
  for (int ww = 1; ww < 8; ++ww) {
    mstar0 = fmaxf(mstar0, m_lds[ww][cq]);
    mstar1 = fmaxf(mstar1, m_lds[ww][16 + cq]);
  }
  float lstar0 = 0.f, lstar1 = 0.f;
#pragma unroll
  for (int ww = 0; ww < 8; ++ww) {
    lstar0 += l_lds[ww][cq]      * exp2f(m_lds[ww][cq]      - mstar0);
    lstar1 += l_lds[ww][16 + cq] * exp2f(m_lds[ww][16 + cq] - mstar1);
  }
  float sc0 = exp2f(m0 - mstar0), sc1 = exp2f(m1 - mstar1);
  if (w == 0 && lane < 16) { lstar_lds[cq] = lstar0; lstar_lds[16 + cq] = lstar1; }

  const int r = w & 3;
  if (w < 4) {
#pragma unroll
    for (int ct = 0; ct < 8; ++ct)
#pragma unroll
      for (int v = 0; v < 4; ++v) {
        o_lds[r][ct * 16 + g4 + v][cq]      = acc[ct][0][v] * sc0;
        o_lds[r][ct * 16 + g4 + v][16 + cq] = acc[ct][1][v] * sc1;
      }
  }
  __syncthreads();
  if (w >= 4) {
#pragma unroll
    for (int ct = 0; ct < 8; ++ct)
#pragma unroll
      for (int v = 0; v < 4; ++v) {
        o_lds[r][ct * 16 + g4 + v][cq]      += acc[ct][0][v] * sc0;
        o_lds[r][ct * 16 + g4 + v][16 + cq] += acc[ct][1][v] * sc1;
      }
  }
  __syncthreads();

  // ---- epilogue: out = gamma * O/l + x ----
  const float g0 = gamma_p[0];
  for (int idx = t; idx < 128 * 32; idx += 512) {
    int c = idx >> 5, qq = idx & 31;
    float o = (o_lds[0][c][qq] + o_lds[1][c][qq] +
               o_lds[2][c][qq] + o_lds[3][c][qq]) / lstar_lds[qq];
    size_t addr = (size_t)(b * 128 + c) * N_VOX + qt0 + qq;
    out[addr] = fmaf(g0, o, x[addr]);
  }
}

// ---------------------------------------------------------------------------
extern "C" void kernel_launch(void* const* d_in, const int* in_sizes, int n_in,
                              void* d_out, int out_size, void* d_ws, size_t ws_size,
                              hipStream_t stream) {
  const float* x     = (const float*)d_in[0];
  const float* wq    = (const float*)d_in[1];
  const float* bq    = (const float*)d_in[2];
  const float* wk    = (const float*)d_in[3];
  const float* bk    = (const float*)d_in[4];
  const float* wv    = (const float*)d_in[5];
  const float* bv    = (const float*)d_in[6];
  const float* gamma = (const float*)d_in[7];
  float* out = (float*)d_out;
  unsigned char* ws8 = (unsigned char*)d_ws;   // 2 MB

  proj_kernel<<<256, 256, 0, stream>>>(x, wq, bq, wk, bk, wv, bv, ws8);
  attn_kernel<<<256, 512, 0, stream>>>(ws8, x, gamma, out);
}

// Round 10
// 31.845 us; speedup vs baseline: 1.1300x; 1.1300x over previous
//
#include <hip/hip_runtime.h>
#include <hip/hip_bf16.h>
#include <math.h>

#define N_VOX 4096
#define P_LN8 2.0794415f   // P stored as exp(s - m - ln8) <= e^(8-ln8) = 372 < 448

typedef __bf16 bf16x4 __attribute__((ext_vector_type(4)));
typedef __bf16 bf16x8 __attribute__((ext_vector_type(8)));
typedef float f32x4 __attribute__((ext_vector_type(4)));
typedef float f32x16 __attribute__((ext_vector_type(16)));

// ws layout (BYTES):
//   qt bf16[2][4096][16] @ 0        (no pad; 32x32x16 K-dim = 16 exactly)
//   kt bf16[2][4096][16] @ 262144
//   vp fp8 packed        @ 524288   1 MB
//     byte: ((b*256 + (j>>4))*4 + (c>>5))*512 + (((j>>3)&1)*32 + (c&31))*8 + (j&7)
#define QT_OFF 0
#define KT_OFF 262144
#define VP_OFF 524288

__device__ __forceinline__ f32x16 mfma32_bf16(bf16x8 a, bf16x8 b, f32x16 c) {
  return __builtin_amdgcn_mfma_f32_32x32x16_bf16(a, b, c, 0, 0, 0);
}
__device__ __forceinline__ f32x16 mfma32_fp8(long a, long b, f32x16 c) {
  return __builtin_amdgcn_mfma_f32_32x32x16_fp8_fp8(a, b, c, 0, 0, 0);
}
__device__ __forceinline__ void pinl(long& v) { asm volatile("" : "+v"(v)); }
__device__ __forceinline__ void pinb(bf16x8& v) { asm volatile("" : "+v"(v)); }

__device__ __forceinline__ unsigned f32_to_fp8x4(float a, float b, float c, float d) {
  int v = __builtin_amdgcn_cvt_pk_fp8_f32(a, b, 0, false);
  v = __builtin_amdgcn_cvt_pk_fp8_f32(c, d, v, true);
  return (unsigned)v;
}
__device__ __forceinline__ unsigned char f32_to_fp8(float a) {
  return (unsigned char)(__builtin_amdgcn_cvt_pk_fp8_f32(a, a, 0, false) & 0xff);
}

// ---------------------------------------------------------------------------
// Kernel 1: q/k/v projections as MFMA GEMM (w staged bf16 in LDS).
// grid = 2 x 128 n-tiles of 32, 256 threads.
// ---------------------------------------------------------------------------
__global__ __launch_bounds__(256) void proj_kernel(
    const float* __restrict__ x,
    const float* __restrict__ wq, const float* __restrict__ bq,
    const float* __restrict__ wk, const float* __restrict__ bk,
    const float* __restrict__ wv, const float* __restrict__ bv,
    unsigned char* __restrict__ ws8) {
  __shared__ __bf16 xs[32 * 136];    // [n][c] pad 136            8.7 KB
  __shared__ __bf16 wb[160 * 136];   // q 0-15, k 16-31, v 32-159 43.5 KB

  const int t   = threadIdx.x;
  const int bid = blockIdx.x;        // 256 = 2 * 128
  const int b   = bid >> 7;
  const int n0  = (bid & 127) * 32;

  for (int i = t; i < 5120; i += 256) {
    int gid = i * 4;
    const float* src = (gid < 2048) ? wq + gid
                     : (gid < 4096) ? wk + (gid - 2048)
                                    : wv + (gid - 4096);
    float4 f = *reinterpret_cast<const float4*>(src);
    int r = gid >> 7, col = gid & 127;
    bf16x4 o;
    o[0] = (__bf16)f.x; o[1] = (__bf16)f.y; o[2] = (__bf16)f.z; o[3] = (__bf16)f.w;
    *reinterpret_cast<bf16x4*>(&wb[r * 136 + col]) = o;
  }
  for (int idx = t; idx < 128 * 8; idx += 256) {
    int c = idx >> 3, v4 = idx & 7;
    float4 xv = *reinterpret_cast<const float4*>(
        x + (size_t)(b * 128 + c) * N_VOX + n0 + v4 * 4);
    xs[(v4 * 4 + 0) * 136 + c] = (__bf16)xv.x;
    xs[(v4 * 4 + 1) * 136 + c] = (__bf16)xv.y;
    xs[(v4 * 4 + 2) * 136 + c] = (__bf16)xv.z;
    xs[(v4 * 4 + 3) * 136 + c] = (__bf16)xv.w;
  }
  __syncthreads();

  const int w = t >> 6, lane = t & 63;
  const int cq = lane & 15, g = lane >> 4, g8 = g * 8, g4 = g * 4;

  __bf16* qt = reinterpret_cast<__bf16*>(ws8 + QT_OFF);
  __bf16* kt = reinterpret_cast<__bf16*>(ws8 + KT_OFF);
  unsigned char* vp = ws8 + VP_OFF;
  const f32x4 zero4 = {0.f, 0.f, 0.f, 0.f};

  for (int ot = w; ot < 10; ot += 4) {
    int wrow = (ot == 0) ? cq : (ot == 1) ? 16 + cq : 32 + (ot - 2) * 16 + cq;
    const float* bias = (ot == 0) ? bq : (ot == 1) ? bk : bv + (ot - 2) * 16;

    f32x4 acc[2] = {zero4, zero4};
#pragma unroll
    for (int ks = 0; ks < 4; ++ks) {
      bf16x8 af = *reinterpret_cast<const bf16x8*>(&wb[wrow * 136 + ks * 32 + g8]);
#pragma unroll
      for (int nf = 0; nf < 2; ++nf) {
        bf16x8 bfr = *reinterpret_cast<const bf16x8*>(
            &xs[(nf * 16 + cq) * 136 + ks * 32 + g8]);
        acc[nf] = __builtin_amdgcn_mfma_f32_16x16x32_bf16(af, bfr, acc[nf], 0, 0, 0);
      }
    }

    float4 bl = *reinterpret_cast<const float4*>(bias + g4);
    const float* blp = reinterpret_cast<const float*>(&bl);
#pragma unroll
    for (int nf = 0; nf < 2; ++nf) {
      int n = n0 + nf * 16 + cq;
      if (ot < 2) {
        bf16x4 pk;
#pragma unroll
        for (int v = 0; v < 4; ++v) pk[v] = (__bf16)(acc[nf][v] + blp[v]);
        __bf16* dst = (ot == 0) ? qt : kt;
        *reinterpret_cast<bf16x4*>(dst + (size_t)(b * 4096 + n) * 16 + g4) = pk;
      } else {
#pragma unroll
        for (int v = 0; v < 4; ++v) {
          float val = acc[nf][v] + blp[v];
          int c = (ot - 2) * 16 + g4 + v;
          vp[(((size_t)(b * 256 + (n >> 4)) * 4 + (c >> 5)) << 9)
             + (((n >> 3) & 1) * 32 + (c & 31)) * 8 + (n & 7)] = f32_to_fp8(val);
        }
      }
    }
  }
}

// ---------------------------------------------------------------------------
// Kernel 2: fused flash attention, 32x32x16 MFMA path.
// grid = 256 (b x 128 q-tiles of 32), 512 thr = 8 waves, wave: 32q x 512 keys.
// Lane q = lane&31 (both halves). QK^T: 2 MFMA/tile (no zero pad).
// Softmax: 31 fmax + 1 shfl. P in-register via cvt_pk + shfl_xor(32).
// PV: 16 fp8 MFMA/tile. No LDS in the K-loop at all.
// ---------------------------------------------------------------------------
__global__ __launch_bounds__(512, 2) void attn_kernel(
    const unsigned char* __restrict__ ws8,
    const float* __restrict__ x,
    const float* __restrict__ gamma_p,
    float* __restrict__ out) {
  __shared__ float o_lds[4][128][33];                 // 67.6 KB
  __shared__ float m_lds[8][32], l_lds[8][32], lstar_lds[32];

  const int t    = threadIdx.x;
  const int w    = t >> 6;
  const int lane = t & 63;
  const int l31  = lane & 31;
  const int hi   = lane >> 5;

  const int raw = blockIdx.x;            // 256
  const int xcd = raw & 7;
  const int b   = xcd >> 2;
  const int qt0 = ((raw >> 3) * 4 + (xcd & 3)) * 32;

  const __bf16* qt = reinterpret_cast<const __bf16*>(ws8 + QT_OFF);
  const __bf16* kt = reinterpret_cast<const __bf16*>(ws8 + KT_OFF);
  const unsigned char* vp = ws8 + VP_OFF;

  // Q B-fragment: col=q=lane&31, k=hi*8+e
  bf16x8 qf = *reinterpret_cast<const bf16x8*>(
      qt + (size_t)(b * 4096 + qt0 + l31) * 16 + hi * 8);

  f32x16 acc[4];
#pragma unroll
  for (int cb = 0; cb < 4; ++cb)
#pragma unroll
    for (int r = 0; r < 16; ++r) acc[cb][r] = 0.f;
  const f32x16 zero16 = acc[0];
  float m = -1e30f, l = 0.f;

  const __bf16* kbase = kt + (size_t)(b * 4096 + l31) * 16 + hi * 8;
  const unsigned char* vbase = vp + (size_t)b * 524288 + lane * 8;

  const int jt_base = w * 8;

  bf16x8 kf0 = *reinterpret_cast<const bf16x8*>(kbase + (size_t)(jt_base * 64) * 16);
  bf16x8 kf1 = *reinterpret_cast<const bf16x8*>(kbase + (size_t)(jt_base * 64 + 32) * 16);

#pragma unroll 1
  for (int tile = 0; tile < 8; ++tile) {
    const int jt = jt_base + tile;
    const int jtn = jt_base + ((tile + 1) & 7);

    // ---- issue 16 V loads (8B each) + 2 next-K loads ----
    long vf[4][4];
#pragma unroll
    for (int jc = 0; jc < 4; ++jc)
#pragma unroll
      for (int cb = 0; cb < 4; ++cb)
        vf[jc][cb] = *reinterpret_cast<const long*>(
            vbase + (((size_t)(jt * 4 + jc) * 4 + cb) << 9));
    bf16x8 kn0 = *reinterpret_cast<const bf16x8*>(kbase + (size_t)(jtn * 64) * 16);
    bf16x8 kn1 = *reinterpret_cast<const bf16x8*>(kbase + (size_t)(jtn * 64 + 32) * 16);

    // ---- QK^T: sf[r] = S^T[j][q], j = (r&3)+8*(r>>2)+4*hi (+32 for sf1) ----
    f32x16 sf0 = mfma32_bf16(kf0, qf, zero16);
    f32x16 sf1 = mfma32_bf16(kf1, qf, zero16);

    // ---- online softmax: each lane owns q = l31, 32 j-values ----
    float tmax = sf0[0];
#pragma unroll
    for (int r = 1; r < 16; ++r) tmax = fmaxf(tmax, sf0[r]);
#pragma unroll
    for (int r = 0; r < 16; ++r) tmax = fmaxf(tmax, sf1[r]);
    tmax = fmaxf(tmax, __shfl_xor(tmax, 32));

    if (__any(tmax > m + 8.0f)) {                    // defer-max
      float mn = fmaxf(m, tmax);
      float sc = __expf(m - mn);
#pragma unroll
      for (int cb = 0; cb < 4; ++cb)
#pragma unroll
        for (int r = 0; r < 16; ++r) acc[cb][r] *= sc;
      l *= sc;
      m = mn;
    }

    float p0[16], p1[16];
    float psum = 0.f;
#pragma unroll
    for (int r = 0; r < 16; ++r) {
      p0[r] = fminf(__expf(sf0[r] - m - P_LN8), 440.f);
      p1[r] = fminf(__expf(sf1[r] - m - P_LN8), 440.f);
      psum += p0[r] + p1[r];
    }
    psum += __shfl_xor(psum, 32);
    l += psum;

    // ---- pack P to fp8 words; W[i] = p[4i..4i+3] ----
    unsigned W0[4], W1[4], X0[4], X1[4];
#pragma unroll
    for (int i = 0; i < 4; ++i) {
      W0[i] = f32_to_fp8x4(p0[4 * i], p0[4 * i + 1], p0[4 * i + 2], p0[4 * i + 3]);
      W1[i] = f32_to_fp8x4(p1[4 * i], p1[4 * i + 1], p1[4 * i + 2], p1[4 * i + 3]);
    }
#pragma unroll
    for (int i = 0; i < 4; ++i) {
      X0[i] = __shfl_xor(W0[i], 32);
      X1[i] = __shfl_xor(W1[i], 32);
    }

    // ---- PV: per j16-chunk jc, B-frag = (word0 = e0..3, word1 = e4..7) ----
#pragma unroll
    for (int jc = 0; jc < 4; ++jc)
#pragma unroll
      for (int cb = 0; cb < 4; ++cb) pinl(vf[jc][cb]);
    pinb(kn0); pinb(kn1);

    __builtin_amdgcn_s_setprio(1);
#pragma unroll
    for (int jc = 0; jc < 4; ++jc) {
      const int pb = (jc & 1) * 2;
      unsigned wd0, wd1;
      if (jc < 2) {
        wd0 = hi ? X0[pb + 1] : W0[pb];
        wd1 = hi ? W0[pb + 1] : X0[pb];
      } else {
        wd0 = hi ? X1[pb + 1] : W1[pb];
        wd1 = hi ? W1[pb + 1] : X1[pb];
      }
      long pf = (long)(((unsigned long long)wd1 << 32) | wd0);
#pragma unroll
      for (int cb = 0; cb < 4; ++cb)
        acc[cb] = mfma32_fp8(vf[jc][cb], pf, acc[cb]);
    }
    __builtin_amdgcn_s_setprio(0);

    kf0 = kn0; kf1 = kn1;
  }

  // ---- cross-wave merge (8 partials) ----
  if (lane < 32) { m_lds[w][lane] = m; l_lds[w][lane] = l; }
  __syncthreads();

  float mstar = m_lds[0][l31];
#pragma unroll
  for (int ww = 1; ww < 8; ++ww) mstar = fmaxf(mstar, m_lds[ww][l31]);
  float lstar = 0.f;
#pragma unroll
  for (int ww = 0; ww < 8; ++ww)
    lstar += l_lds[ww][l31] * __expf(m_lds[ww][l31] - mstar);
  float sc = __expf(m - mstar);
  if (w == 0 && lane < 32) lstar_lds[lane] = lstar;

  const int rr = w & 3;
  if (w < 4) {
#pragma unroll
    for (int cb = 0; cb < 4; ++cb)
#pragma unroll
      for (int r = 0; r < 16; ++r)
        o_lds[rr][cb * 32 + (r & 3) + 8 * (r >> 2) + 4 * hi][l31] = acc[cb][r] * sc;
  }
  __syncthreads();
  if (w >= 4) {
#pragma unroll
    for (int cb = 0; cb < 4; ++cb)
#pragma unroll
      for (int r = 0; r < 16; ++r)
        o_lds[rr][cb * 32 + (r & 3) + 8 * (r >> 2) + 4 * hi][l31] += acc[cb][r] * sc;
  }
  __syncthreads();

  // ---- epilogue: out = gamma * O/l + x ----
  const float g0 = gamma_p[0];
  for (int idx = t; idx < 128 * 32; idx += 512) {
    int c = idx >> 5, qq = idx & 31;
    float o = (o_lds[0][c][qq] + o_lds[1][c][qq] +
               o_lds[2][c][qq] + o_lds[3][c][qq]) / lstar_lds[qq];
    size_t addr = (size_t)(b * 128 + c) * N_VOX + qt0 + qq;
    out[addr] = fmaf(g0, o, x[addr]);
  }
}

// ---------------------------------------------------------------------------
extern "C" void kernel_launch(void* const* d_in, const int* in_sizes, int n_in,
                              void* d_out, int out_size, void* d_ws, size_t ws_size,
                              hipStream_t stream) {
  const float* x     = (const float*)d_in[0];
  const float* wq    = (const float*)d_in[1];
  const float* bq    = (const float*)d_in[2];
  const float* wk    = (const float*)d_in[3];
  const float* bk    = (const float*)d_in[4];
  const float* wv    = (const float*)d_in[5];
  const float* bv    = (const float*)d_in[6];
  const float* gamma = (const float*)d_in[7];
  float* out = (float*)d_out;
  unsigned char* ws8 = (unsigned char*)d_ws;   // 1.5 MB

  proj_kernel<<<256, 256, 0, stream>>>(x, wq, bq, wk, bk, wv, bv, ws8);
  attn_kernel<<<256, 512, 0, stream>>>(ws8, x, gamma, out);
}